// Round 5
// baseline (816.622 us; speedup 1.0000x reference)
//
#include <hip/hip_runtime.h>

#define BB 512
#define LL 1024
#define DD 16
#define HH 64
#define CH 16    // timesteps per chunk
#define GS 196   // sh_gi row stride (floats), padded

typedef _Float16 half8 __attribute__((ext_vector_type(8)));
typedef float floatx4 __attribute__((ext_vector_type(4)));

struct U4 { unsigned x, y, z, w; };

__device__ __forceinline__ float sigmoidf_(float x) {
    return __builtin_amdgcn_rcpf(1.0f + __expf(-x));
}
__device__ __forceinline__ float tanhf_(float x) {
    x = fminf(fmaxf(x, -15.0f), 15.0f);
    float e = __expf(2.0f * x);
    return (e - 1.0f) * __builtin_amdgcn_rcpf(e + 1.0f);
}
__device__ __forceinline__ void split_(float v, unsigned& h, unsigned& l) {
    _Float16 hf = (_Float16)v;
    float rr = v - (float)hf;
    _Float16 lf = (_Float16)rr;
    h = (unsigned)__builtin_bit_cast(unsigned short, hf);
    l = (unsigned)__builtin_bit_cast(unsigned short, lf);
}
__device__ __forceinline__ unsigned pack_hl(float v) {
    unsigned h, l; split_(v, h, l);
    return h | (l << 16);
}
__device__ __forceinline__ float bcast_(float v, int k) {
    return __uint_as_float(__builtin_amdgcn_readlane(__float_as_uint(v), k));
}
__device__ __forceinline__ half8 h8(U4 u) { return __builtin_bit_cast(half8, u); }

#define MFMA(a, b, c) __builtin_amdgcn_mfma_f32_16x16x32_f16((a), (b), (c), 0, 0, 0)

// One wave per (dir, batch): 1024 blocks x 64 threads, 1 wave/SIMD, zero
// barriers. Whh resident in 192 arch VGPRs (fp32-exact recurrence); the
// step loop is pure issue: 64 readlane + 192 fma + gates. gi = Wih*x is
// precomputed per 16-step chunk via MFMA (A-frags reloaded from LDS so they
// don't occupy registers across the step loop); y via shfl butterfly.
__global__ __launch_bounds__(64, 1) void brios_main(
    const float* __restrict__ x, const float* __restrict__ dt,
    const float* __restrict__ f_Wih, const float* __restrict__ f_Whh,
    const float* __restrict__ f_bih, const float* __restrict__ f_bhh,
    const float* __restrict__ f_gamma, const float* __restrict__ f_Wout,
    const float* __restrict__ f_bout,
    const float* __restrict__ b_Wih, const float* __restrict__ b_Whh,
    const float* __restrict__ b_bih, const float* __restrict__ b_bhh,
    const float* __restrict__ b_gamma, const float* __restrict__ b_Wout,
    const float* __restrict__ b_bout,
    float* __restrict__ out)
{
    const int lane = threadIdx.x;
    const int m    = lane & 15;
    const int g4   = lane >> 4;
    const int dir  = blockIdx.x >> 9;
    const int b    = blockIdx.x & 511;

    const float* Wih  = dir ? b_Wih  : f_Wih;
    const float* Whh  = dir ? b_Whh  : f_Whh;
    const float* bih  = dir ? b_bih  : f_bih;
    const float* bhh  = dir ? b_bhh  : f_bhh;
    const float* Wout = dir ? b_Wout : f_Wout;
    float gam = dir ? b_gamma[0] : f_gamma[0];
    gam = fminf(fmaxf(gam, 1e-4f), 10.0f);
    const float bo = dir ? b_bout[0] : f_bout[0];

    __shared__ alignas(16) unsigned sh_agi[12][HH][4]; // Wih A-frags, per-lane
    __shared__ alignas(16) unsigned sh_x[CH][DD];      // packed x chunk
    __shared__ alignas(16) float    sh_gi[CH][GS];     // Wih*x for chunk
    __shared__ float sh_dcy[CH];
    __shared__ float sh_y[CH];

    // ---- build Wih A-fragments once, park them in LDS (temps die here)
#pragma unroll
    for (int tt = 0; tt < 12; ++tt) {
        unsigned v[4];
#pragma unroll
        for (int r2 = 0; r2 < 4; ++r2) {
            unsigned h0, l0;
            split_(Wih[(size_t)(tt * 16 + m) * DD + g4 * 4 + r2], h0, l0);
            v[r2] = h0 | (l0 << 16);      // K-pair (w_hi, w_lo)
        }
        *(U4*)&sh_agi[tt][lane][0] = U4{v[0], v[1], v[2], v[3]};
    }

    // ---- Whh resident: lane j holds rows j, 64+j, 128+j (192 VGPRs)
    float wr[HH], wz[HH], wn[HH];
#pragma unroll
    for (int k = 0; k < HH; ++k) {
        wr[k] = Whh[(size_t)(      lane) * HH + k];
        wz[k] = Whh[(size_t)( 64 + lane) * HH + k];
        wn[k] = Whh[(size_t)(128 + lane) * HH + k];
    }
    const float br  = bih[lane]      + bhh[lane];
    const float bz  = bih[64 + lane] + bhh[64 + lane];
    const float bni = bih[128 + lane];
    const float bnh = bhh[128 + lane];
    const float wo  = Wout[lane];

    float h_reg = 0.0f;      // lane j holds h[j]
    float* yd = out + (size_t)(1 + dir) * (BB * LL);

#pragma unroll 1
    for (int c = 0; c < LL / CH; ++c) {
        const int sbase = c * CH;
        const int t_low = dir ? (LL - CH - sbase) : sbase;

        // ---- stage x (1 float4/lane, packed f16 hi/lo) and decay factors
        {
            int tq = lane >> 2, d4 = lane & 3;
            float4 v = *(const float4*)(x + ((size_t)b * LL + t_low + tq) * DD + d4 * 4);
            int sl = dir ? (CH - 1 - tq) : tq;
            *(U4*)&sh_x[sl][d4 * 4] =
                U4{pack_hl(v.x), pack_hl(v.y), pack_hl(v.z), pack_hl(v.w)};
            if (lane < CH) {
                int t = dir ? (LL - 1 - (sbase + lane)) : (sbase + lane);
                float dv = dt[(size_t)b * LL + t];
                dv = fminf(fmaxf(dv, 0.0f), 1e6f);
                sh_dcy[lane] = __expf(-gam * dv);
            }
        }
        // single wave: program order + compiler waitcnts, no barrier

        // ---- gi = Wih * x via MFMA (B col = step m, K = 16 d x hi/lo)
        {
            U4 p = *(const U4*)&sh_x[m][g4 * 4];
            U4 ph = U4{__builtin_amdgcn_perm(p.x, p.x, 0x01000100u),
                       __builtin_amdgcn_perm(p.y, p.y, 0x01000100u),
                       __builtin_amdgcn_perm(p.z, p.z, 0x01000100u),
                       __builtin_amdgcn_perm(p.w, p.w, 0x01000100u)};
            U4 pl = U4{__builtin_amdgcn_perm(p.x, p.x, 0x03020302u),
                       __builtin_amdgcn_perm(p.y, p.y, 0x03020302u),
                       __builtin_amdgcn_perm(p.z, p.z, 0x03020302u),
                       __builtin_amdgcn_perm(p.w, p.w, 0x03020302u)};
            half8 Bh = h8(ph), Bl = h8(pl);
#pragma unroll
            for (int tt = 0; tt < 12; ++tt) {
                U4 a4 = *(const U4*)&sh_agi[tt][lane][0];
                floatx4 g = {0.0f, 0.0f, 0.0f, 0.0f};
                g = MFMA(h8(a4), Bh, g);   // (w_hi+w_lo)*x_hi
                g = MFMA(h8(a4), Bl, g);   // + (w_hi+w_lo)*x_lo
                // C: col = m (step), rows = tt*16 + g4*4 + reg
                *(floatx4*)&sh_gi[m][tt * 16 + g4 * 4] = g;
            }
        }

        // ---- recurrent steps: no barriers, no cross-wave LDS
#pragma unroll 1
        for (int i = 0; i < CH; ++i) {
            float gir = sh_gi[i][lane];
            float giz = sh_gi[i][64 + lane];
            float gin = sh_gi[i][128 + lane];
            float dcy = sh_dcy[i];
            float hbar = dcy * h_reg;

            float a0 = 0.0f, a1 = 0.0f, z0 = 0.0f, z1 = 0.0f, n0 = 0.0f, n1 = 0.0f;
#pragma unroll
            for (int k = 0; k < HH; k += 2) {
                float hk0 = bcast_(hbar, k);
                float hk1 = bcast_(hbar, k + 1);
                a0 = fmaf(wr[k], hk0, a0);
                z0 = fmaf(wz[k], hk0, z0);
                n0 = fmaf(wn[k], hk0, n0);
                a1 = fmaf(wr[k + 1], hk1, a1);
                z1 = fmaf(wz[k + 1], hk1, z1);
                n1 = fmaf(wn[k + 1], hk1, n1);
            }
            float r = sigmoidf_((a0 + a1) + gir + br);
            float z = sigmoidf_((z0 + z1) + giz + bz);
            float n = tanhf_((gin + bni) + r * ((n0 + n1) + bnh));
            h_reg = n + z * (hbar - n);

            float v = wo * h_reg;
#pragma unroll
            for (int sft = 32; sft >= 1; sft >>= 1) v += __shfl_xor(v, sft, 64);
            sh_y[i] = v + bo;    // uniform across lanes
        }

        // ---- flush y coalesced
        if (lane < CH) {
            int s = sbase + lane;
            int t = dir ? (LL - 1 - s) : s;
            yd[(size_t)b * LL + t] = sh_y[lane];
        }
    }
}

__global__ __launch_bounds__(256) void brios_avg(float* __restrict__ out)
{
    int i = blockIdx.x * blockDim.x + threadIdx.x;
    const int n4 = (BB * LL) / 4;
    if (i < n4) {
        const float4* yf = (const float4*)(out + (size_t)BB * LL);
        const float4* yb = (const float4*)(out + (size_t)2 * BB * LL);
        float4 a = yf[i], b2 = yb[i];
        float4 r;
        r.x = 0.5f * (a.x + b2.x);
        r.y = 0.5f * (a.y + b2.y);
        r.z = 0.5f * (a.z + b2.z);
        r.w = 0.5f * (a.w + b2.w);
        ((float4*)out)[i] = r;
    }
}

extern "C" void kernel_launch(void* const* d_in, const int* in_sizes, int n_in,
                              void* d_out, int out_size, void* d_ws, size_t ws_size,
                              hipStream_t stream) {
    const float* x       = (const float*)d_in[0];
    const float* dt      = (const float*)d_in[1];
    const float* f_Wih   = (const float*)d_in[2];
    const float* f_Whh   = (const float*)d_in[3];
    const float* f_bih   = (const float*)d_in[4];
    const float* f_bhh   = (const float*)d_in[5];
    const float* f_gamma = (const float*)d_in[6];
    const float* f_Wout  = (const float*)d_in[7];
    const float* f_bout  = (const float*)d_in[8];
    const float* b_Wih   = (const float*)d_in[9];
    const float* b_Whh   = (const float*)d_in[10];
    const float* b_bih   = (const float*)d_in[11];
    const float* b_bhh   = (const float*)d_in[12];
    const float* b_gamma = (const float*)d_in[13];
    const float* b_Wout  = (const float*)d_in[14];
    const float* b_bout  = (const float*)d_in[15];
    float* out = (float*)d_out;

    brios_main<<<1024, 64, 0, stream>>>(x, dt,
        f_Wih, f_Whh, f_bih, f_bhh, f_gamma, f_Wout, f_bout,
        b_Wih, b_Whh, b_bih, b_bhh, b_gamma, b_Wout, b_bout, out);

    const int n4 = (BB * LL) / 4;
    brios_avg<<<(n4 + 255) / 256, 256, 0, stream>>>(out);
}